// Round 1
// baseline (12.219 us; speedup 1.0000x reference)
//
#include <hip/hip_runtime.h>

// NeRF ray rendering: R=1024 rays, N=576 samples (384 log-spaced inner + 192 outer).
// Outputs flat: image[1024*3] | invdepth[1024] | l_dist[1]  = 4097 floats.
//
// Strategy: one wave (64 lanes) per ray, 9 chunks of 64 samples.
//  - alpha compositing via shuffle-based inclusive product scan (transmittance)
//  - distortion loss in O(N) using sortedness of t:
//      sum_ij w_i w_j |t_i - t_j| = 2 * sum_i w_i (t_i * W_i - T_i),
//      W_i / T_i = exclusive prefix sums of w and w*t.
//  - z_vals / deltas / z_lin computed on the fly from the sample index.

#define NSAMP 576
#define NRAYS 1024

__device__ __forceinline__ float zexp(int i) {
    // exponent array: concat(linspace(-1.2,0,384), linspace(0,2,192))
    if (i < 384) return -1.2f + (float)i * (1.2f / 383.0f);
    return (float)(i - 384) * (2.0f / 191.0f);
}
__device__ __forceinline__ float zval(int i) {
    const float LOG2_10 = 3.3219280948873623f;
    return exp2f(zexp(i) * LOG2_10);
}
__device__ __forceinline__ float tval(int i) {
    return (zexp(i) + 1.2f) * (1.0f / 3.2f);
}

__global__ __launch_bounds__(256) void render_kernel(
    const float* __restrict__ sigmas,   // [1024, 576]
    const float* __restrict__ rgbs,     // [1024, 576, 3]
    float* __restrict__ out,            // [4097]
    float* __restrict__ wsum)           // [1024] per-ray distortion (already *2)
{
    const float LOG2_E = 1.4426950408889634f;
    const int lane = threadIdx.x & 63;
    const int ray  = blockIdx.x * 4 + (threadIdx.x >> 6);

    const float* __restrict__ sig = sigmas + (size_t)ray * NSAMP;
    const float* __restrict__ rgb = rgbs  + (size_t)ray * NSAMP * 3;

    float runP = 1.0f;   // running transmittance product across chunks
    float runW = 0.0f;   // running sum of w
    float runT = 0.0f;   // running sum of w*t
    float imR = 0.0f, imG = 0.0f, imB = 0.0f, invd = 0.0f, dist = 0.0f;

    #pragma unroll
    for (int k = 0; k < 9; ++k) {
        const int s = k * 64 + lane;
        const float sg = sig[s];
        const float r0 = rgb[s * 3 + 0];
        const float g0 = rgb[s * 3 + 1];
        const float b0 = rgb[s * 3 + 2];

        const float z = zval(s);
        const float delta = (s == NSAMP - 1) ? 1e10f : (zval(s + 1) - z);
        const float t = tval(s);

        const float e  = exp2f(-sg * delta * LOG2_E);  // exp(-sigma*delta)
        const float alpha = 1.0f - e;
        const float om = e + 1e-10f;                   // 1 - alpha + EPS

        // inclusive product scan of om across the wave
        float p = om;
        #pragma unroll
        for (int off = 1; off < 64; off <<= 1) {
            float o = __shfl_up(p, off, 64);
            if (lane >= off) p *= o;
        }
        float exP = __shfl_up(p, 1, 64);     // exclusive prefix product
        if (lane == 0) exP = 1.0f;

        const float w  = alpha * (runP * exP);
        const float wt = w * t;

        // inclusive sum scans of w and w*t
        float sw = w, swt = wt;
        #pragma unroll
        for (int off = 1; off < 64; off <<= 1) {
            float a = __shfl_up(sw,  off, 64);
            float b = __shfl_up(swt, off, 64);
            if (lane >= off) { sw += a; swt += b; }
        }
        const float exW  = sw  - w;          // exclusive prefix sums
        const float exWT = swt - wt;

        dist += w * (t * (runW + exW) - (runT + exWT));
        imR  += w * r0;
        imG  += w * g0;
        imB  += w * b0;
        invd += w / z;

        runP *= __shfl(p,   63, 64);
        runW += __shfl(sw,  63, 64);
        runT += __shfl(swt, 63, 64);
    }

    // wave reductions (5 values)
    #pragma unroll
    for (int off = 32; off; off >>= 1) {
        imR  += __shfl_down(imR,  off, 64);
        imG  += __shfl_down(imG,  off, 64);
        imB  += __shfl_down(imB,  off, 64);
        invd += __shfl_down(invd, off, 64);
        dist += __shfl_down(dist, off, 64);
    }

    if (lane == 0) {
        out[ray * 3 + 0] = imR;
        out[ray * 3 + 1] = imG;
        out[ray * 3 + 2] = imB;
        out[3 * NRAYS + ray] = invd;
        wsum[ray] = 2.0f * dist;   // full double-sum = 2 * upper-triangle
    }
}

__global__ __launch_bounds__(256) void reduce_kernel(
    const float* __restrict__ wsum, float* __restrict__ out)
{
    const int tid = threadIdx.x;
    float v = wsum[tid] + wsum[tid + 256] + wsum[tid + 512] + wsum[tid + 768];
    #pragma unroll
    for (int off = 32; off; off >>= 1) v += __shfl_down(v, off, 64);

    __shared__ float partial[4];
    if ((tid & 63) == 0) partial[tid >> 6] = v;
    __syncthreads();
    if (tid == 0)
        out[3 * NRAYS + NRAYS] =
            (partial[0] + partial[1] + partial[2] + partial[3]) * (1.0f / 1024.0f);
}

extern "C" void kernel_launch(void* const* d_in, const int* in_sizes, int n_in,
                              void* d_out, int out_size, void* d_ws, size_t ws_size,
                              hipStream_t stream) {
    const float* sigmas = (const float*)d_in[0];
    const float* rgbs   = (const float*)d_in[1];
    float* out = (float*)d_out;
    float* ws  = (float*)d_ws;

    render_kernel<<<NRAYS / 4, 256, 0, stream>>>(sigmas, rgbs, out, ws);
    reduce_kernel<<<1, 256, 0, stream>>>(ws, out);
}